// Round 1
// baseline (705.598 us; speedup 1.0000x reference)
//
#include <hip/hip_runtime.h>
#include <stddef.h>

// ---------------------------------------------------------------------------
// CustomNet forward: conv1(1->32,3x3)+ReLU -> conv2(32->64,3x3)+ReLU ->
// maxpool2x2 -> fc1(9216->128)+ReLU -> fc2(128->10).  B=2048, fp32.
// Round 1: fp32 baseline. conv1+conv2+pool fused per-image (h1 lives in LDS),
// fc1 as split-K tiled GEMM, fc2 tiny kernel.
// ---------------------------------------------------------------------------

#define NIMG 2048

// LDS overlay offsets (floats) for the fused conv kernel.
// [0, 21632)              h1 (32 x 26 x 26)
// [21632, 40064)          w2t (288 x 64)  -- loaded AFTER h1 is computed
// x/w1/b1 staging overlays the (not-yet-loaded) w2 region during phase 1/2.
#define H1OFF 0
#define W2OFF 21632
#define XOFF  21632           // 784 floats
#define W1OFF (21632 + 784)   // 288 floats
#define B1OFF (21632 + 784 + 288) // 32 floats
#define SMEM_FLOATS 40064     // 160256 bytes <= 160 KiB

// transpose w2 [64][32][3][3] -> w2t[(ic*9+kyx)][oc]
__global__ void k_w2t(const float* __restrict__ w2, float* __restrict__ w2t) {
    int i = blockIdx.x * 256 + threadIdx.x;
    if (i < 64 * 288) {
        int oc = i / 288, r = i % 288;
        w2t[r * 64 + oc] = w2[i];
    }
}

__launch_bounds__(512)
__global__ void k_conv_fused(const float* __restrict__ x,
                             const float* __restrict__ w1,
                             const float* __restrict__ b1,
                             const float* __restrict__ w2t,
                             const float* __restrict__ b2,
                             float* __restrict__ pooled) {
    __shared__ float smem[SMEM_FLOATS];
    const int tid = threadIdx.x;
    const int img = blockIdx.x;

    // ---- phase 1: stage x, w1, b1 ----
    const float* xg = x + (size_t)img * 784;
    for (int i = tid; i < 784; i += 512) smem[XOFF + i] = xg[i];
    for (int i = tid; i < 288; i += 512) smem[W1OFF + i] = w1[i];
    if (tid < 32) smem[B1OFF + tid] = b1[tid];
    __syncthreads();

    // ---- phase 2: conv1 + relu -> h1 in LDS [32][26][26] ----
    for (int e = tid; e < 32 * 676; e += 512) {
        int oc = e / 676, r = e % 676;
        int y = r / 26, xx = r % 26;
        const float* wp = &smem[W1OFF + oc * 9];
        const float* xp = &smem[XOFF + y * 28 + xx];
        float s = smem[B1OFF + oc];
        s = fmaf(wp[0], xp[0],  s); s = fmaf(wp[1], xp[1],  s); s = fmaf(wp[2], xp[2],  s);
        s = fmaf(wp[3], xp[28], s); s = fmaf(wp[4], xp[29], s); s = fmaf(wp[5], xp[30], s);
        s = fmaf(wp[6], xp[56], s); s = fmaf(wp[7], xp[57], s); s = fmaf(wp[8], xp[58], s);
        smem[H1OFF + e] = fmaxf(s, 0.0f);
    }
    __syncthreads();

    // ---- phase 3: stage all of w2t (overwrites x/w1/b1 overlay) ----
    for (int i = tid; i < 18432; i += 512) smem[W2OFF + i] = w2t[i];
    __syncthreads();

    // ---- phase 4: conv2 + relu + maxpool ----
    // tasks: 8 oc-groups (8 oc each) x 144 pooled positions = 1152
    for (int task = tid; task < 1152; task += 512) {
        int ocg = task / 144;
        int pos = task % 144;
        int py = pos / 12, px = pos % 12;
        int y0 = py * 2, x0 = px * 2;
        int oc0 = ocg * 8;
        float acc[8][4];
        #pragma unroll
        for (int j = 0; j < 8; j++)
            #pragma unroll
            for (int q = 0; q < 4; q++) acc[j][q] = 0.0f;

        const float* hbase = &smem[H1OFF + y0 * 26 + x0];
        for (int ic = 0; ic < 32; ic++) {
            const float* hp = hbase + ic * 676;
            const float* wp = &smem[W2OFF + ic * 9 * 64 + oc0];
            #pragma unroll
            for (int ky = 0; ky < 3; ky++) {
                #pragma unroll
                for (int kx = 0; kx < 3; kx++) {
                    float h00 = hp[ky * 26 + kx];
                    float h01 = hp[ky * 26 + kx + 1];
                    float h10 = hp[(ky + 1) * 26 + kx];
                    float h11 = hp[(ky + 1) * 26 + kx + 1];
                    const float* wq = wp + (ky * 3 + kx) * 64;
                    #pragma unroll
                    for (int j = 0; j < 8; j++) {
                        float wv = wq[j];
                        acc[j][0] = fmaf(wv, h00, acc[j][0]);
                        acc[j][1] = fmaf(wv, h01, acc[j][1]);
                        acc[j][2] = fmaf(wv, h10, acc[j][2]);
                        acc[j][3] = fmaf(wv, h11, acc[j][3]);
                    }
                }
            }
        }
        float* outp = pooled + (size_t)img * 9216 + (size_t)oc0 * 144 + pos;
        #pragma unroll
        for (int j = 0; j < 8; j++) {
            float m = fmaxf(fmaxf(acc[j][0], acc[j][1]), fmaxf(acc[j][2], acc[j][3]));
            outp[j * 144] = fmaxf(m + b2[oc0 + j], 0.0f);
        }
    }
}

// fc1 split-K GEMM: out[m][n] = sum_k pooled[m][k] * fc1_w[n][k]
// M=2048, N=128, K=9216.  16 M-tiles x 32 K-chunks (288 each) -> partials.
#define FC1_KC 32
#define FC1_CK 288

__launch_bounds__(256)
__global__ void k_fc1(const float* __restrict__ A,   // pooled [2048][9216]
                      const float* __restrict__ W,   // fc1_w  [128][9216]
                      float* __restrict__ part) {    // [32][2048][128]
    __shared__ float As[32 * 132];
    __shared__ float Ws[32 * 132];
    const int t = threadIdx.x;
    const int m0 = blockIdx.x * 128;
    const int k0 = blockIdx.y * FC1_CK;

    float acc[8][8];
    #pragma unroll
    for (int i = 0; i < 8; i++)
        #pragma unroll
        for (int j = 0; j < 8; j++) acc[i][j] = 0.0f;

    const int lr = t >> 1;            // 0..127 : row of tile
    const int lh = (t & 1) * 16;      // k-half offset
    const int tm = (t >> 4) * 8;      // 0..120 : my 8 rows
    const int tn = (t & 15) * 8;      // 0..120 : my 8 cols

    for (int ks = 0; ks < FC1_CK; ks += 32) {
        #pragma unroll
        for (int i = 0; i < 4; i++) {
            int kk = lh + 4 * i;
            float4 va = *reinterpret_cast<const float4*>(
                &A[(size_t)(m0 + lr) * 9216 + k0 + ks + kk]);
            As[(kk + 0) * 132 + lr] = va.x;
            As[(kk + 1) * 132 + lr] = va.y;
            As[(kk + 2) * 132 + lr] = va.z;
            As[(kk + 3) * 132 + lr] = va.w;
            float4 vw = *reinterpret_cast<const float4*>(
                &W[(size_t)lr * 9216 + k0 + ks + kk]);
            Ws[(kk + 0) * 132 + lr] = vw.x;
            Ws[(kk + 1) * 132 + lr] = vw.y;
            Ws[(kk + 2) * 132 + lr] = vw.z;
            Ws[(kk + 3) * 132 + lr] = vw.w;
        }
        __syncthreads();
        #pragma unroll
        for (int kk = 0; kk < 32; kk++) {
            float4 a0 = *reinterpret_cast<const float4*>(&As[kk * 132 + tm]);
            float4 a1 = *reinterpret_cast<const float4*>(&As[kk * 132 + tm + 4]);
            float4 w0 = *reinterpret_cast<const float4*>(&Ws[kk * 132 + tn]);
            float4 w1v = *reinterpret_cast<const float4*>(&Ws[kk * 132 + tn + 4]);
            float a[8] = {a0.x, a0.y, a0.z, a0.w, a1.x, a1.y, a1.z, a1.w};
            float w[8] = {w0.x, w0.y, w0.z, w0.w, w1v.x, w1v.y, w1v.z, w1v.w};
            #pragma unroll
            for (int i = 0; i < 8; i++)
                #pragma unroll
                for (int j = 0; j < 8; j++)
                    acc[i][j] = fmaf(a[i], w[j], acc[i][j]);
        }
        __syncthreads();
    }

    float* pp = part + (size_t)blockIdx.y * (2048 * 128) + (size_t)m0 * 128;
    #pragma unroll
    for (int i = 0; i < 8; i++)
        #pragma unroll
        for (int j = 0; j < 8; j++)
            pp[(size_t)(tm + i) * 128 + tn + j] = acc[i][j];
}

__global__ void k_fc1_reduce(const float* __restrict__ part,
                             const float* __restrict__ b,
                             float* __restrict__ out) {
    int i = blockIdx.x * 256 + threadIdx.x;   // over 2048*128
    if (i < 2048 * 128) {
        float s = b[i & 127];
        #pragma unroll 8
        for (int kc = 0; kc < FC1_KC; kc++) s += part[(size_t)kc * (2048 * 128) + i];
        out[i] = fmaxf(s, 0.0f);
    }
}

__global__ void k_fc2(const float* __restrict__ h,   // [2048][128]
                      const float* __restrict__ w,   // [10][128]
                      const float* __restrict__ b,   // [10]
                      float* __restrict__ out) {     // [2048][10]
    __shared__ float hs[16 * 128];
    __shared__ float ws[10 * 128];
    __shared__ float bs[10];
    const int t = threadIdx.x;
    const int m0 = blockIdx.x * 16;
    for (int i = t; i < 16 * 128; i += 256) hs[i] = h[(size_t)m0 * 128 + i];
    for (int i = t; i < 1280; i += 256) ws[i] = w[i];
    if (t < 10) bs[t] = b[t];
    __syncthreads();
    int r = t / 16, c = t % 16;
    if (c < 10) {
        float s = bs[c];
        const float* hp = &hs[r * 128];
        const float* wp = &ws[c * 128];
        #pragma unroll
        for (int k = 0; k < 128; k++) s = fmaf(hp[k], wp[k], s);
        out[(size_t)(m0 + r) * 10 + c] = s;
    }
}

extern "C" void kernel_launch(void* const* d_in, const int* in_sizes, int n_in,
                              void* d_out, int out_size, void* d_ws, size_t ws_size,
                              hipStream_t stream) {
    const float* x     = (const float*)d_in[0];
    const float* w1    = (const float*)d_in[1];
    const float* b1    = (const float*)d_in[2];
    const float* w2    = (const float*)d_in[3];
    const float* b2    = (const float*)d_in[4];
    const float* fc1_w = (const float*)d_in[5];
    const float* fc1_b = (const float*)d_in[6];
    const float* fc2_w = (const float*)d_in[7];
    const float* fc2_b = (const float*)d_in[8];
    float* out = (float*)d_out;

    float* ws = (float*)d_ws;
    float* w2t    = ws;                         // 18432
    float* pooled = ws + 18432;                 // 2048*9216 = 18874368
    float* part   = pooled + (size_t)2048 * 9216;      // 32*2048*128 = 8388608
    float* fc1out = part + (size_t)FC1_KC * 2048 * 128; // 262144

    k_w2t<<<(18432 + 255) / 256, 256, 0, stream>>>(w2, w2t);
    k_conv_fused<<<NIMG, 512, 0, stream>>>(x, w1, b1, w2t, b2, pooled);
    k_fc1<<<dim3(16, FC1_KC), 256, 0, stream>>>(pooled, fc1_w, part);
    k_fc1_reduce<<<(2048 * 128 + 255) / 256, 256, 0, stream>>>(part, fc1_b, fc1out);
    k_fc2<<<NIMG / 16, 256, 0, stream>>>(fc1out, fc2_w, fc2_b, out);
}

// Round 2
// 174.303 us; speedup vs baseline: 4.0481x; 4.0481x over previous
//
#include <hip/hip_runtime.h>
#include <stddef.h>

// ---------------------------------------------------------------------------
// CustomNet forward. Round 2: conv2 as per-image MFMA implicit-GEMM (bf16),
// conv1 fp32 -> bf16 h1 in LDS position-major, in-lane 2x2 maxpool.
// fc1 fp32 split-K GEMM unchanged, fc2 unchanged.
// ---------------------------------------------------------------------------

#define NIMG 2048

typedef __attribute__((ext_vector_type(8))) short short8;
typedef __attribute__((ext_vector_type(4))) float f32x4;

__device__ inline ushort f2bf(float f) {
    unsigned u = __builtin_bit_cast(unsigned, f);
    unsigned r = (u + 0x7fff + ((u >> 16) & 1)) >> 16;   // RTNE, inputs >=0 finite
    return (ushort)r;
}

// pack w2 [64][32][3][3] into per-lane MFMA B-fragments:
// bfr[((nt*9 + kyx)*64 + lane)*8 + j] = bf16(w2[oc=nt*16+(lane&15)][ic=8*(lane>>4)+j][kyx])
__global__ void k_w2pack(const float* __restrict__ w2, ushort* __restrict__ bfr) {
    int i = blockIdx.x * 256 + threadIdx.x;
    if (i < 18432) {
        int j = i & 7;
        int l = (i >> 3) & 63;
        int t = i >> 9;            // nt*9 + kyx
        int kyx = t % 9, nt = t / 9;
        int oc = nt * 16 + (l & 15);
        int ic = 8 * (l >> 4) + j;
        bfr[i] = f2bf(w2[oc * 288 + ic * 9 + kyx]);
    }
}

// LDS: h1p (676 pos x 32 ic, bf16) = 43264 B, then xs (784 f32) = 3136 B.
// pooled staging (64*144 f32 = 36864 B) overlays h1p after last MFMA.
#define SMEM_FLOATS 11600   // 46400 B

__launch_bounds__(512)
__global__ void k_conv_fused(const float* __restrict__ x,
                             const float* __restrict__ w1,
                             const float* __restrict__ b1,
                             const ushort* __restrict__ bfr,
                             const float* __restrict__ b2,
                             float* __restrict__ pooled) {
    __shared__ float smemf[SMEM_FLOATS];
    const int tid = threadIdx.x;
    const int img = blockIdx.x;
    const int lane = tid & 63;
    const int w = tid >> 6;

    float* xs = smemf + 10816;          // 43264 B offset

    // ---- stage x ----
    const float* xg = x + (size_t)img * 784;
    for (int i = tid; i < 784; i += 512) xs[i] = xg[i];

    // ---- conv1 weights/bias in registers (ocg fixed per thread) ----
    const int ocg = tid & 3;
    float w1r[72], b1r[8];
    #pragma unroll
    for (int j = 0; j < 8; j++) {
        b1r[j] = b1[ocg * 8 + j];
        #pragma unroll
        for (int q = 0; q < 9; q++) w1r[j * 9 + q] = w1[(ocg * 8 + j) * 9 + q];
    }
    __syncthreads();

    // ---- conv1 + relu -> h1p[pos][ic] bf16 ----
    for (int it = 0; it < 6; it++) {
        int pos = (tid >> 2) + it * 128;
        if (pos < 676) {
            int y = pos / 26, xx = pos - y * 26;
            const float* xp = &xs[y * 28 + xx];
            float xv[9];
            xv[0] = xp[0];  xv[1] = xp[1];  xv[2] = xp[2];
            xv[3] = xp[28]; xv[4] = xp[29]; xv[5] = xp[30];
            xv[6] = xp[56]; xv[7] = xp[57]; xv[8] = xp[58];
            short8 pk;
            #pragma unroll
            for (int j = 0; j < 8; j++) {
                float s = b1r[j];
                #pragma unroll
                for (int q = 0; q < 9; q++) s = fmaf(w1r[j * 9 + q], xv[q], s);
                pk[j] = (short)f2bf(fmaxf(s, 0.0f));
            }
            *(short8*)((char*)smemf + pos * 64 + ocg * 16) = pk;
        }
    }
    __syncthreads();

    // ---- conv2 MFMA + in-lane maxpool ----
    // wave w: ntile pair p = w&1 (oc tiles 2p, 2p+1), m-group g = w>>1.
    const int p = w & 1;
    const int g = w >> 1;

    short8 bf[2][9];
    #pragma unroll
    for (int j = 0; j < 2; j++)
        #pragma unroll
        for (int kyx = 0; kyx < 9; kyx++)
            bf[j][kyx] = *(const short8*)&bfr[(((2 * p + j) * 9 + kyx) * 64 + lane) * 8];

    const int row = lane & 15;     // A row / output oc-lane
    const int ic8 = lane >> 4;     // A k-group / output qid-lane
    float b2v[2];
    b2v[0] = b2[(2 * p) * 16 + row];
    b2v[1] = b2[(2 * p + 1) * 16 + row];

    float pv[9][2];
    #pragma unroll 1
    for (int i = 0; i < 9; i++) {
        int mt = g + i * 4;                 // 36 m-tiles over 4 groups
        int m = mt * 16 + row;
        int qid = m >> 2;
        int de = m & 3;
        int py = qid / 12, px = qid - py * 12;
        int yy = py * 2 + (de >> 1);
        int xx2 = px * 2 + (de & 1);
        int pos = yy * 26 + xx2;
        const char* abase = (const char*)smemf + pos * 64 + ic8 * 16;

        f32x4 acc0 = {0.f, 0.f, 0.f, 0.f};
        f32x4 acc1 = {0.f, 0.f, 0.f, 0.f};
        #pragma unroll
        for (int ky = 0; ky < 3; ky++)
            #pragma unroll
            for (int kx = 0; kx < 3; kx++) {
                short8 a = *(const short8*)(abase + (ky * 26 + kx) * 64);
                acc0 = __builtin_amdgcn_mfma_f32_16x16x32_bf16(a, bf[0][ky * 3 + kx], acc0, 0, 0, 0);
                acc1 = __builtin_amdgcn_mfma_f32_16x16x32_bf16(a, bf[1][ky * 3 + kx], acc1, 0, 0, 0);
            }
        pv[i][0] = fmaxf(fmaxf(acc0[0], acc0[1]), fmaxf(acc0[2], acc0[3]));
        pv[i][1] = fmaxf(fmaxf(acc1[0], acc1[1]), fmaxf(acc1[2], acc1[3]));
    }
    __syncthreads();    // all waves done reading h1p

    // ---- stage pooled [oc][qid] f32 in LDS (overlays h1p), then coalesced out ----
    float* ps = smemf;
    #pragma unroll
    for (int i = 0; i < 9; i++) {
        int mt = g + i * 4;
        int qid = mt * 4 + ic8;
        int oc0 = (2 * p) * 16 + row;
        ps[oc0 * 144 + qid]        = fmaxf(pv[i][0] + b2v[0], 0.0f);
        ps[(oc0 + 16) * 144 + qid] = fmaxf(pv[i][1] + b2v[1], 0.0f);
    }
    __syncthreads();

    float4* og = (float4*)(pooled + (size_t)img * 9216);
    const float4* psv = (const float4*)ps;
    for (int i = tid; i < 2304; i += 512) og[i] = psv[i];
}

// fc1 split-K GEMM: out[m][n] = sum_k pooled[m][k] * fc1_w[n][k]
#define FC1_KC 32
#define FC1_CK 288

__launch_bounds__(256)
__global__ void k_fc1(const float* __restrict__ A,   // pooled [2048][9216]
                      const float* __restrict__ W,   // fc1_w  [128][9216]
                      float* __restrict__ part) {    // [32][2048][128]
    __shared__ float As[32 * 132];
    __shared__ float Ws[32 * 132];
    const int t = threadIdx.x;
    const int m0 = blockIdx.x * 128;
    const int k0 = blockIdx.y * FC1_CK;

    float acc[8][8];
    #pragma unroll
    for (int i = 0; i < 8; i++)
        #pragma unroll
        for (int j = 0; j < 8; j++) acc[i][j] = 0.0f;

    const int lr = t >> 1;
    const int lh = (t & 1) * 16;
    const int tm = (t >> 4) * 8;
    const int tn = (t & 15) * 8;

    for (int ks = 0; ks < FC1_CK; ks += 32) {
        #pragma unroll
        for (int i = 0; i < 4; i++) {
            int kk = lh + 4 * i;
            float4 va = *reinterpret_cast<const float4*>(
                &A[(size_t)(m0 + lr) * 9216 + k0 + ks + kk]);
            As[(kk + 0) * 132 + lr] = va.x;
            As[(kk + 1) * 132 + lr] = va.y;
            As[(kk + 2) * 132 + lr] = va.z;
            As[(kk + 3) * 132 + lr] = va.w;
            float4 vw = *reinterpret_cast<const float4*>(
                &W[(size_t)lr * 9216 + k0 + ks + kk]);
            Ws[(kk + 0) * 132 + lr] = vw.x;
            Ws[(kk + 1) * 132 + lr] = vw.y;
            Ws[(kk + 2) * 132 + lr] = vw.z;
            Ws[(kk + 3) * 132 + lr] = vw.w;
        }
        __syncthreads();
        #pragma unroll
        for (int kk = 0; kk < 32; kk++) {
            float4 a0 = *reinterpret_cast<const float4*>(&As[kk * 132 + tm]);
            float4 a1 = *reinterpret_cast<const float4*>(&As[kk * 132 + tm + 4]);
            float4 w0 = *reinterpret_cast<const float4*>(&Ws[kk * 132 + tn]);
            float4 w1v = *reinterpret_cast<const float4*>(&Ws[kk * 132 + tn + 4]);
            float a[8] = {a0.x, a0.y, a0.z, a0.w, a1.x, a1.y, a1.z, a1.w};
            float wv[8] = {w0.x, w0.y, w0.z, w0.w, w1v.x, w1v.y, w1v.z, w1v.w};
            #pragma unroll
            for (int i = 0; i < 8; i++)
                #pragma unroll
                for (int j = 0; j < 8; j++)
                    acc[i][j] = fmaf(a[i], wv[j], acc[i][j]);
        }
        __syncthreads();
    }

    float* pp = part + (size_t)blockIdx.y * (2048 * 128) + (size_t)m0 * 128;
    #pragma unroll
    for (int i = 0; i < 8; i++)
        #pragma unroll
        for (int j = 0; j < 8; j++)
            pp[(size_t)(tm + i) * 128 + tn + j] = acc[i][j];
}

__global__ void k_fc1_reduce(const float* __restrict__ part,
                             const float* __restrict__ b,
                             float* __restrict__ out) {
    int i = blockIdx.x * 256 + threadIdx.x;
    if (i < 2048 * 128) {
        float s = b[i & 127];
        #pragma unroll 8
        for (int kc = 0; kc < FC1_KC; kc++) s += part[(size_t)kc * (2048 * 128) + i];
        out[i] = fmaxf(s, 0.0f);
    }
}

__global__ void k_fc2(const float* __restrict__ h,
                      const float* __restrict__ w,
                      const float* __restrict__ b,
                      float* __restrict__ out) {
    __shared__ float hs[16 * 128];
    __shared__ float ws[10 * 128];
    __shared__ float bs[10];
    const int t = threadIdx.x;
    const int m0 = blockIdx.x * 16;
    for (int i = t; i < 16 * 128; i += 256) hs[i] = h[(size_t)m0 * 128 + i];
    for (int i = t; i < 1280; i += 256) ws[i] = w[i];
    if (t < 10) bs[t] = b[t];
    __syncthreads();
    int r = t / 16, c = t % 16;
    if (c < 10) {
        float s = bs[c];
        const float* hp = &hs[r * 128];
        const float* wp = &ws[c * 128];
        #pragma unroll
        for (int k = 0; k < 128; k++) s = fmaf(hp[k], wp[k], s);
        out[(size_t)(m0 + r) * 10 + c] = s;
    }
}

extern "C" void kernel_launch(void* const* d_in, const int* in_sizes, int n_in,
                              void* d_out, int out_size, void* d_ws, size_t ws_size,
                              hipStream_t stream) {
    const float* x     = (const float*)d_in[0];
    const float* w1    = (const float*)d_in[1];
    const float* b1    = (const float*)d_in[2];
    const float* w2    = (const float*)d_in[3];
    const float* b2    = (const float*)d_in[4];
    const float* fc1_w = (const float*)d_in[5];
    const float* fc1_b = (const float*)d_in[6];
    const float* fc2_w = (const float*)d_in[7];
    const float* fc2_b = (const float*)d_in[8];
    float* out = (float*)d_out;

    char* wsb = (char*)d_ws;
    ushort* bfr   = (ushort*)wsb;                        // 36864 B
    float* pooled = (float*)(wsb + 36864);               // 2048*9216 f32
    float* part   = pooled + (size_t)2048 * 9216;        // 32*2048*128 f32
    float* fc1out = part + (size_t)FC1_KC * 2048 * 128;  // 262144 f32

    k_w2pack<<<72, 256, 0, stream>>>(w2, bfr);
    k_conv_fused<<<NIMG, 512, 0, stream>>>(x, w1, b1, bfr, b2, pooled);
    k_fc1<<<dim3(16, FC1_KC), 256, 0, stream>>>(pooled, fc1_w, part);
    k_fc1_reduce<<<(2048 * 128 + 255) / 256, 256, 0, stream>>>(part, fc1_b, fc1out);
    k_fc2<<<NIMG / 16, 256, 0, stream>>>(fc1out, fc2_w, fc2_b, out);
}

// Round 3
// 93.071 us; speedup vs baseline: 7.5813x; 1.8728x over previous
//
#include <hip/hip_runtime.h>
#include <stddef.h>

// ---------------------------------------------------------------------------
// CustomNet forward. Round 3:
//  - conv: direct bf16 permuted-layout pooled stores (no LDS re-staging),
//          conv1 x-reads vectorized (pos-pairs).
//  - fc1: bf16 MFMA split-K GEMM (pooled/fc1_w pre-permuted to match the
//         conv lanes' natural output order), fp32 partials.
//  - fc2: fuses the split-K reduce + bias + relu + final GEMV.
// ---------------------------------------------------------------------------

#define NIMG 2048

typedef __attribute__((ext_vector_type(8))) short short8;
typedef __attribute__((ext_vector_type(4))) float f32x4;

__device__ inline ushort f2bf(float f) {
    unsigned u = __builtin_bit_cast(unsigned, f);
    unsigned r = (u + 0x7fff + ((u >> 16) & 1)) >> 16;   // RTNE, finite
    return (ushort)r;
}

// pack w2 [64][32][3][3] into per-lane MFMA B-fragments:
// bfr[((nt*9 + kyx)*64 + lane)*8 + j] = bf16(w2[oc=nt*16+(lane&15)][ic=8*(lane>>4)+j][kyx])
__global__ void k_w2pack(const float* __restrict__ w2, ushort* __restrict__ bfr) {
    int i = blockIdx.x * 256 + threadIdx.x;
    if (i < 18432) {
        int j = i & 7;
        int l = (i >> 3) & 63;
        int t = i >> 9;
        int kyx = t % 9, nt = t / 9;
        int oc = nt * 16 + (l & 15);
        int ic = 8 * (l >> 4) + j;
        bfr[i] = f2bf(w2[oc * 288 + ic * 9 + kyx]);
    }
}

// Permute fc1_w columns into the conv kernel's natural pooled output order
// and convert to bf16.  kp = ((wv*9+i)*64+lane)*2 + j  ->
//   oc=(2*(wv&1)+j)*16+(lane&15); mt=(wv>>1)+i*4; qid=mt*4+(lane>>4);
//   orig_k = oc*144 + qid.
__global__ void k_fc1wpack(const float* __restrict__ fc1_w, ushort* __restrict__ wp) {
    int idx = blockIdx.x * 256 + threadIdx.x;
    if (idx < 128 * 9216) {
        int n = idx / 9216, kp = idx % 9216;
        int j = kp & 1;
        int lane = (kp >> 1) & 63;
        int t = kp >> 7;
        int i = t % 9, wv = t / 9;
        int oc = (2 * (wv & 1) + j) * 16 + (lane & 15);
        int mt = (wv >> 1) + i * 4;
        int qid = mt * 4 + (lane >> 4);
        wp[idx] = f2bf(fc1_w[(size_t)n * 9216 + oc * 144 + qid]);
    }
}

// LDS: h1p (676 pos x 32 ic bf16) = 43264 B, xs (784 f32) = 3136 B.
#define SMEM_FLOATS 11600   // 46400 B

__launch_bounds__(512)
__global__ void k_conv_fused(const float* __restrict__ x,
                             const float* __restrict__ w1,
                             const float* __restrict__ b1,
                             const ushort* __restrict__ bfr,
                             const float* __restrict__ b2,
                             ushort* __restrict__ pooled) {   // bf16, permuted k
    __shared__ float smemf[SMEM_FLOATS];
    const int tid = threadIdx.x;
    const int img = blockIdx.x;
    const int lane = tid & 63;
    const int w = tid >> 6;

    float* xs = smemf + 10816;

    // ---- stage x ----
    const float* xg = x + (size_t)img * 784;
    for (int i = tid; i < 784; i += 512) xs[i] = xg[i];

    // ---- conv1 weights/bias in registers (ocg fixed per thread) ----
    const int ocg = tid & 3;
    float w1r[72], b1r[8];
    #pragma unroll
    for (int j = 0; j < 8; j++) {
        b1r[j] = b1[ocg * 8 + j];
        #pragma unroll
        for (int q = 0; q < 9; q++) w1r[j * 9 + q] = w1[(ocg * 8 + j) * 9 + q];
    }
    __syncthreads();

    // ---- conv1 + relu -> h1p[pos][ic] bf16 (pos-pairs, vector x reads) ----
    #pragma unroll
    for (int it = 0; it < 3; it++) {
        int pid = (tid >> 2) + it * 128;
        if (pid < 338) {
            int y = pid / 13;
            int px2 = (pid - y * 13) * 2;
            const float* xr = &xs[y * 28 + px2];
            float xv[3][4];
            #pragma unroll
            for (int r = 0; r < 3; r++) {
                float2 u = *(const float2*)&xr[r * 28];
                float2 v = *(const float2*)&xr[r * 28 + 2];
                xv[r][0] = u.x; xv[r][1] = u.y; xv[r][2] = v.x; xv[r][3] = v.y;
            }
            short8 pk0, pk1;
            #pragma unroll
            for (int j = 0; j < 8; j++) {
                float s0 = b1r[j], s1 = b1r[j];
                #pragma unroll
                for (int ky = 0; ky < 3; ky++)
                    #pragma unroll
                    for (int kx = 0; kx < 3; kx++) {
                        float wv = w1r[j * 9 + ky * 3 + kx];
                        s0 = fmaf(wv, xv[ky][kx], s0);
                        s1 = fmaf(wv, xv[ky][kx + 1], s1);
                    }
                pk0[j] = (short)f2bf(fmaxf(s0, 0.0f));
                pk1[j] = (short)f2bf(fmaxf(s1, 0.0f));
            }
            int pos0 = y * 26 + px2;
            *(short8*)((char*)smemf + pos0 * 64 + ocg * 16) = pk0;
            *(short8*)((char*)smemf + pos0 * 64 + 64 + ocg * 16) = pk1;
        }
    }
    __syncthreads();

    // ---- conv2 MFMA + in-lane maxpool + direct permuted bf16 store ----
    const int p = w & 1;
    const int g = w >> 1;

    short8 bf[2][9];
    #pragma unroll
    for (int j = 0; j < 2; j++)
        #pragma unroll
        for (int kyx = 0; kyx < 9; kyx++)
            bf[j][kyx] = *(const short8*)&bfr[(((2 * p + j) * 9 + kyx) * 64 + lane) * 8];

    const int row = lane & 15;
    const int ic8 = lane >> 4;
    float b2v[2];
    b2v[0] = b2[(2 * p) * 16 + row];
    b2v[1] = b2[(2 * p + 1) * 16 + row];

    unsigned* pp = (unsigned*)(pooled + (size_t)img * 9216);

    #pragma unroll 1
    for (int i = 0; i < 9; i++) {
        int mt = g + i * 4;
        int m = mt * 16 + row;
        int qid = m >> 2;
        int de = m & 3;
        int py = qid / 12, px = qid - py * 12;
        int yy = py * 2 + (de >> 1);
        int xx2 = px * 2 + (de & 1);
        int pos = yy * 26 + xx2;
        const char* abase = (const char*)smemf + pos * 64 + ic8 * 16;

        f32x4 acc0 = {0.f, 0.f, 0.f, 0.f};
        f32x4 acc1 = {0.f, 0.f, 0.f, 0.f};
        #pragma unroll
        for (int ky = 0; ky < 3; ky++)
            #pragma unroll
            for (int kx = 0; kx < 3; kx++) {
                short8 a = *(const short8*)(abase + (ky * 26 + kx) * 64);
                acc0 = __builtin_amdgcn_mfma_f32_16x16x32_bf16(a, bf[0][ky * 3 + kx], acc0, 0, 0, 0);
                acc1 = __builtin_amdgcn_mfma_f32_16x16x32_bf16(a, bf[1][ky * 3 + kx], acc1, 0, 0, 0);
            }
        float v0 = fmaxf(fmaxf(fmaxf(acc0[0], acc0[1]), fmaxf(acc0[2], acc0[3])) + b2v[0], 0.0f);
        float v1 = fmaxf(fmaxf(fmaxf(acc1[0], acc1[1]), fmaxf(acc1[2], acc1[3])) + b2v[1], 0.0f);
        pp[(w * 9 + i) * 64 + lane] = (unsigned)f2bf(v0) | ((unsigned)f2bf(v1) << 16);
    }
}

// fc1: bf16 MFMA split-K GEMM.  M=2048, N=128, K=9216 (permuted).
// grid (16 m-tiles, 16 k-splits), block 512 (8 waves, 2x4), BM=128 BN=128 BK=64.
#define FC1_SPLIT 16
#define FC1_CHUNK 576   // 9 BK-steps of 64

__launch_bounds__(512)
__global__ void k_fc1(const ushort* __restrict__ A,    // pooled bf16 [2048][9216]
                      const ushort* __restrict__ Wp,   // packed fc1_w bf16 [128][9216]
                      float* __restrict__ part) {      // [16][2048][128]
    __shared__ ushort As[128 * 64];
    __shared__ ushort Ws[128 * 64];
    char* Ac = (char*)As;
    char* Wc = (char*)Ws;

    const int t = threadIdx.x;
    const int lane = t & 63;
    const int wv = t >> 6;
    const int wm = wv >> 2;        // 0..1
    const int wn = wv & 3;         // 0..3
    const int lr = lane & 15;
    const int lk = lane >> 4;
    const int m0 = blockIdx.x * 128;
    const int kc0 = blockIdx.y * FC1_CHUNK;

    const int trow = t >> 2;       // 0..127
    const int seg = t & 3;         // 0..3
    const int wb0 = trow * 128 + seg * 32;
    const int sw = (trow & 7) << 4;

    const ushort* Ab = A + (size_t)(m0 + trow) * 9216 + kc0 + seg * 16;
    const ushort* Wb = Wp + (size_t)trow * 9216 + kc0 + seg * 16;

    f32x4 acc[4][2];
    #pragma unroll
    for (int mf = 0; mf < 4; mf++)
        #pragma unroll
        for (int nf = 0; nf < 2; nf++) acc[mf][nf] = (f32x4){0.f, 0.f, 0.f, 0.f};

    short8 ra0 = *(const short8*)(Ab);
    short8 ra1 = *(const short8*)(Ab + 8);
    short8 rw0 = *(const short8*)(Wb);
    short8 rw1 = *(const short8*)(Wb + 8);
    short8 na0, na1, nw0, nw1;

    for (int s = 0; s < 9; s++) {
        *(short8*)(Ac + (wb0 ^ sw)) = ra0;
        *(short8*)(Ac + ((wb0 + 16) ^ sw)) = ra1;
        *(short8*)(Wc + (wb0 ^ sw)) = rw0;
        *(short8*)(Wc + ((wb0 + 16) ^ sw)) = rw1;
        __syncthreads();
        if (s < 8) {
            const ushort* An = Ab + (s + 1) * 64;
            const ushort* Wn = Wb + (s + 1) * 64;
            na0 = *(const short8*)(An);
            na1 = *(const short8*)(An + 8);
            nw0 = *(const short8*)(Wn);
            nw1 = *(const short8*)(Wn + 8);
        }
        #pragma unroll
        for (int ks = 0; ks < 2; ks++) {
            short8 af[4], bfr2[2];
            #pragma unroll
            for (int mf = 0; mf < 4; mf++) {
                int r = wm * 64 + mf * 16 + lr;
                af[mf] = *(const short8*)(Ac + ((r * 128 + ks * 64 + lk * 16) ^ ((r & 7) << 4)));
            }
            #pragma unroll
            for (int nf = 0; nf < 2; nf++) {
                int n = wn * 32 + nf * 16 + lr;
                bfr2[nf] = *(const short8*)(Wc + ((n * 128 + ks * 64 + lk * 16) ^ ((n & 7) << 4)));
            }
            #pragma unroll
            for (int mf = 0; mf < 4; mf++)
                #pragma unroll
                for (int nf = 0; nf < 2; nf++)
                    acc[mf][nf] = __builtin_amdgcn_mfma_f32_16x16x32_bf16(af[mf], bfr2[nf], acc[mf][nf], 0, 0, 0);
        }
        __syncthreads();
        if (s < 8) { ra0 = na0; ra1 = na1; rw0 = nw0; rw1 = nw1; }
    }

    float* pb = part + (size_t)blockIdx.y * (2048 * 128);
    #pragma unroll
    for (int mf = 0; mf < 4; mf++)
        #pragma unroll
        for (int nf = 0; nf < 2; nf++) {
            int mrow = m0 + wm * 64 + mf * 16 + lk * 4;
            int ncol = wn * 32 + nf * 16 + lr;
            #pragma unroll
            for (int q = 0; q < 4; q++)
                pb[(size_t)(mrow + q) * 128 + ncol] = acc[mf][nf][q];
        }
}

// fc2: reduce split-K partials + fc1 bias + relu, then 128->10 GEMV.
__global__ void k_fc2(const float* __restrict__ part,   // [16][2048][128]
                      const float* __restrict__ fc1_b,
                      const float* __restrict__ fc2_w,  // [10][128]
                      const float* __restrict__ fc2_b,
                      float* __restrict__ out) {        // [2048][10]
    __shared__ float hs[16 * 128];
    __shared__ float wsm[10 * 128];
    __shared__ float bsm[10];
    const int t = threadIdx.x;
    const int m0 = blockIdx.x * 16;
    for (int i = t; i < 1280; i += 256) wsm[i] = fc2_w[i];
    if (t < 10) bsm[t] = fc2_b[t];
    #pragma unroll
    for (int e = 0; e < 8; e++) {
        int i = t + e * 256;              // over 16*128
        int r = i >> 7, c = i & 127;
        float s = fc1_b[c];
        #pragma unroll
        for (int kc = 0; kc < FC1_SPLIT; kc++)
            s += part[(size_t)kc * (2048 * 128) + (size_t)(m0 + r) * 128 + c];
        hs[i] = fmaxf(s, 0.0f);
    }
    __syncthreads();
    int r = t / 16, c = t % 16;
    if (c < 10) {
        float s = bsm[c];
        const float* hp = &hs[r * 128];
        const float* wp = &wsm[c * 128];
        #pragma unroll
        for (int k = 0; k < 128; k++) s = fmaf(hp[k], wp[k], s);
        out[(size_t)(m0 + r) * 10 + c] = s;
    }
}

extern "C" void kernel_launch(void* const* d_in, const int* in_sizes, int n_in,
                              void* d_out, int out_size, void* d_ws, size_t ws_size,
                              hipStream_t stream) {
    const float* x     = (const float*)d_in[0];
    const float* w1    = (const float*)d_in[1];
    const float* b1    = (const float*)d_in[2];
    const float* w2    = (const float*)d_in[3];
    const float* b2    = (const float*)d_in[4];
    const float* fc1_w = (const float*)d_in[5];
    const float* fc1_b = (const float*)d_in[6];
    const float* fc2_w = (const float*)d_in[7];
    const float* fc2_b = (const float*)d_in[8];
    float* out = (float*)d_out;

    char* wsb = (char*)d_ws;
    ushort* bfr    = (ushort*)wsb;                       // 36864 B
    ushort* wp     = (ushort*)(wsb + 36864);             // 2359296 B
    ushort* pooled = (ushort*)(wsb + 2396160);           // 37748736 B
    float*  part   = (float*)(wsb + 40144896);           // 16777216 B

    k_w2pack<<<72, 256, 0, stream>>>(w2, bfr);
    k_fc1wpack<<<4608, 256, 0, stream>>>(fc1_w, wp);
    k_conv_fused<<<NIMG, 512, 0, stream>>>(x, w1, b1, bfr, b2, pooled);
    k_fc1<<<dim3(16, FC1_SPLIT), 512, 0, stream>>>(pooled, wp, part);
    k_fc2<<<NIMG / 16, 256, 0, stream>>>(part, fc1_b, fc2_w, fc2_b, out);
}